// Round 8
// baseline (805.199 us; speedup 1.0000x reference)
//
#include <hip/hip_runtime.h>

typedef unsigned short u16;
typedef unsigned int u32;

#define NN 8192
#define CAP 128

typedef __attribute__((ext_vector_type(8))) short short8;
typedef __attribute__((ext_vector_type(4))) float floatx4;

__device__ __forceinline__ u16 f2bf(float f) {
    union { float f; u32 i; } w;
    w.f = f;
    u32 i = w.i;
    u32 r = (i + 0x7FFFu + ((i >> 16) & 1u)) >> 16;
    return (u16)r;
}
__device__ __forceinline__ float lo_bf(u32 v) {
    union { u32 i; float f; } w;
    w.i = v << 16;
    return w.f;
}
__device__ __forceinline__ float hi_bf(u32 v) {
    union { u32 i; float f; } w;
    w.i = v & 0xFFFF0000u;
    return w.f;
}
__device__ __forceinline__ float softplusf(float x) {
    return fmaxf(x, 0.0f) + log1pf(expf(-fabsf(x)));
}

// ---------------- concat [emb | pos] (f32) -> feat0 bf16 [8192 x 128] ----------------
__global__ void concat_feat(const float* __restrict__ emb, const float* __restrict__ pos,
                            u16* __restrict__ out) {
    int idx = blockIdx.x * 256 + threadIdx.x;   // 8192*128 total
    int i = idx >> 7, f = idx & 127;
    float v = (f < 125) ? emb[i * 125 + f] : pos[i * 3 + (f - 125)];
    out[idx] = f2bf(v);
}

// ---------------- wave-per-row pass over f32 adjacency ----------------
__global__ __launch_bounds__(256) void build_graph(
    const float* __restrict__ adj, int* __restrict__ deg,
    float* __restrict__ snorm, u32* __restrict__ edges)
{
    const int wave = threadIdx.x >> 6, lane = threadIdx.x & 63;
    const int i = blockIdx.x * 4 + wave;
    __shared__ int cnt[4];
    if (threadIdx.x < 4) cnt[threadIdx.x] = 0;
    __syncthreads();
    const uint4* rowp = (const uint4*)(adj + (size_t)i * NN);
    u32* erow = edges + (size_t)i * CAP;
#pragma unroll 4
    for (int it = 0; it < 32; ++it) {            // 32 * 64 lanes * 4 f32 = 8192
        uint4 v = rowp[it * 64 + lane];
        int jb = (it * 64 + lane) * 4;
        u32 w[4] = { v.x, v.y, v.z, v.w };
#pragma unroll
        for (int e = 0; e < 4; ++e) {
            int j = jb + e;
            if ((i != j) && ((w[e] & 0x7FFFFFFFu) != 0)) {
                int slot = atomicAdd(&cnt[wave], 1);   // LDS atomic, wave-local
                if (slot < CAP) erow[slot] = (u32)j;
            }
        }
    }
    __syncthreads();
    if (lane == 0) {
        int c = cnt[wave];
        deg[i] = c;
        snorm[i] = rsqrtf((float)max(c, 1));
    }
}

// ---------------- SpMM (R4-exact): wave per dst node, uint4 per lane ----------------
__global__ __launch_bounds__(256) void spmm_kernel(
    const u32* __restrict__ edges, const int* __restrict__ deg,
    const float* __restrict__ snorm,
    const uint4* __restrict__ feat4, uint4* __restrict__ out4, int Fq /* = F/8 */)
{
    __shared__ int   sh_i[4][CAP];
    __shared__ float sh_w[4][CAP];
    const int wave = threadIdx.x >> 6, lane = threadIdx.x & 63;
    const int j = blockIdx.x * 4 + wave;
    const int cnt = min(deg[j], CAP);
    for (int c = lane; c < cnt; c += 64) {
        int i = (int)edges[(size_t)j * CAP + c];
        sh_i[wave][c] = i;
        sh_w[wave][c] = snorm[i];
    }
    __syncthreads();
    if (lane < Fq) {
        float a[8] = {};
#pragma unroll 4
        for (int c = 0; c < cnt; ++c) {
            uint4 v = feat4[(size_t)sh_i[wave][c] * Fq + lane];
            float w = sh_w[wave][c];
            a[0] += w * lo_bf(v.x); a[1] += w * hi_bf(v.x);
            a[2] += w * lo_bf(v.y); a[3] += w * hi_bf(v.y);
            a[4] += w * lo_bf(v.z); a[5] += w * hi_bf(v.z);
            a[6] += w * lo_bf(v.w); a[7] += w * hi_bf(v.w);
        }
        float sj = snorm[j];
        uint4 o;
        o.x = (u32)f2bf(a[0] * sj) | ((u32)f2bf(a[1] * sj) << 16);
        o.y = (u32)f2bf(a[2] * sj) | ((u32)f2bf(a[3] * sj) << 16);
        o.z = (u32)f2bf(a[4] * sj) | ((u32)f2bf(a[5] * sj) << 16);
        o.w = (u32)f2bf(a[6] * sj) | ((u32)f2bf(a[7] * sj) << 16);
        out4[(size_t)j * Fq + lane] = o;
    }
}

// ---------------- 32x32 tiled transpose W[K,N] f32 -> WT[N,K] bf16 ----------------
__global__ void transpose_k(const float* __restrict__ W, u16* __restrict__ WT, int K, int N) {
    __shared__ float tile[32][33];
    int bx = blockIdx.x * 32;   // n
    int by = blockIdx.y * 32;   // k
    int tx = threadIdx.x & 31, ty = threadIdx.x >> 5;  // 256 threads
#pragma unroll
    for (int yy = ty; yy < 32; yy += 8)
        tile[yy][tx] = W[(size_t)(by + yy) * N + bx + tx];
    __syncthreads();
#pragma unroll
    for (int yy = ty; yy < 32; yy += 8)
        WT[(size_t)(bx + yy) * K + by + tx] = f2bf(tile[tx][yy]);
}

// ---------------- GEMM (R4-exact): BM=64, BN=128, BK=32 ----------------
__global__ __launch_bounds__(256, 2) void gemm_bias_softplus(
    const u16* __restrict__ A, const u16* __restrict__ BT,
    const float* __restrict__ bias, float* __restrict__ outf, u16* __restrict__ outb,
    int M, int N, int K)
{
    __shared__ u16 lA[64 * 32];    // [m][k] 4KB
    __shared__ u16 lB[128 * 32];   // [n][k] 8KB
    const int tid = threadIdx.x;
    const int wave = tid >> 6;
    const int lane = tid & 63;
    const int q = lane >> 4;
    const int m16 = lane & 15;
    const int wm = (wave >> 1) * 32;
    const int wn = (wave & 1) * 64;
    const int bm = blockIdx.x, bn = blockIdx.y;

    const int srow = tid >> 2;            // 0..63
    const int scol = (tid & 3) * 8;       // element offset within 32-wide k-tile
    const u16* gA  = A  + (size_t)(bm * 64 + srow) * K + scol;
    const u16* gB0 = BT + (size_t)(bn * 128 + srow) * K + scol;
    const u16* gB1 = gB0 + (size_t)64 * K;
    short8* lAp  = (short8*)lA + tid;
    short8* lBp0 = (short8*)lB + tid;
    short8* lBp1 = (short8*)lB + 256 + tid;

    floatx4 acc[2][4] = {};

    for (int k0 = 0; k0 < K; k0 += 32) {
        short8 va  = *(const short8*)(gA  + k0);
        short8 vb0 = *(const short8*)(gB0 + k0);
        short8 vb1 = *(const short8*)(gB1 + k0);
        *lAp  = va;
        *lBp0 = vb0;
        *lBp1 = vb1;
        __syncthreads();

        short8 af[2], bfr[4];
#pragma unroll
        for (int im = 0; im < 2; ++im)
            af[im] = *(const short8*)&lA[(wm + im * 16 + m16) * 32 + q * 8];
#pragma unroll
        for (int in = 0; in < 4; ++in)
            bfr[in] = *(const short8*)&lB[(wn + in * 16 + m16) * 32 + q * 8];
#pragma unroll
        for (int im = 0; im < 2; ++im)
#pragma unroll
            for (int in = 0; in < 4; ++in)
                acc[im][in] = __builtin_amdgcn_mfma_f32_16x16x32_bf16(
                    af[im], bfr[in], acc[im][in], 0, 0, 0);
        __syncthreads();
    }

#pragma unroll
    for (int im = 0; im < 2; ++im) {
#pragma unroll
        for (int in = 0; in < 4; ++in) {
            int col = bn * 128 + wn + in * 16 + m16;
            float bvf = bias[col];
#pragma unroll
            for (int r = 0; r < 4; ++r) {
                int row = bm * 64 + wm + im * 16 + q * 4 + r;
                float v = acc[im][in][r] + bvf;
                v = softplusf(v);
                if (outf) outf[(size_t)row * N + col] = v;
                else      outb[(size_t)row * N + col] = f2bf(v);
            }
        }
    }
}

// ATTRIBUTION ROUND: every kernel is launched TWICE with identical args.
// All kernels are idempotent (same inputs -> same bytes rewritten), so results
// are unchanged; dur_delta vs the 583us R4 baseline = true pipeline cost.
extern "C" void kernel_launch(void* const* d_in, const int* in_sizes, int n_in,
                              void* d_out, int out_size, void* d_ws, size_t ws_size,
                              hipStream_t stream)
{
    const float* atom_pos = (const float*)d_in[0];
    const float* dist_adj = (const float*)d_in[1];
    const float* atom_emb = (const float*)d_in[2];
    const float* Wm[4] = { (const float*)d_in[3], (const float*)d_in[5],
                           (const float*)d_in[7], (const float*)d_in[9] };
    const float* bv[4] = { (const float*)d_in[4], (const float*)d_in[6],
                           (const float*)d_in[8], (const float*)d_in[10] };

    char* p = (char*)d_ws;
    auto alloc = [&](size_t n) { char* r = p; p += (n + 255) & ~(size_t)255; return r; };
    int*   deg   = (int*)alloc(NN * 4);
    float* snorm = (float*)alloc(NN * 4);
    u32*   edges = (u32*)alloc((size_t)NN * CAP * 4);
    u16*   wt[4];
    wt[0] = (u16*)alloc(512 * 128 * 2);
    wt[1] = (u16*)alloc(512 * 512 * 2);
    wt[2] = (u16*)alloc(512 * 512 * 2);
    wt[3] = (u16*)alloc(512 * 512 * 2);
    u16* buf0 = (u16*)alloc((size_t)NN * 512 * 2);
    u16* buf1 = (u16*)alloc((size_t)NN * 512 * 2);

    for (int rep = 0; rep < 2; ++rep)
        concat_feat<<<(NN * 128) / 256, 256, 0, stream>>>(atom_emb, atom_pos, buf0);
    for (int rep = 0; rep < 2; ++rep)
        build_graph<<<NN / 4, 256, 0, stream>>>(dist_adj, deg, snorm, edges);
    for (int rep = 0; rep < 2; ++rep) {
        transpose_k<<<dim3(512 / 32, 128 / 32), 256, 0, stream>>>(Wm[0], wt[0], 128, 512);
        transpose_k<<<dim3(512 / 32, 512 / 32), 256, 0, stream>>>(Wm[1], wt[1], 512, 512);
        transpose_k<<<dim3(512 / 32, 512 / 32), 256, 0, stream>>>(Wm[2], wt[2], 512, 512);
        transpose_k<<<dim3(512 / 32, 512 / 32), 256, 0, stream>>>(Wm[3], wt[3], 512, 512);
    }

    const u16* feat = buf0;
    int F = 128;
    for (int l = 0; l < 4; ++l) {
        for (int rep = 0; rep < 2; ++rep)
            spmm_kernel<<<NN / 4, 256, 0, stream>>>(edges, deg, snorm,
                                                    (const uint4*)feat, (uint4*)buf1, F / 8);
        float* outf = (l == 3) ? (float*)d_out : nullptr;
        u16*   outb = (l == 3) ? nullptr : buf0;
        for (int rep = 0; rep < 2; ++rep)
            gemm_bias_softplus<<<dim3(NN / 64, 512 / 128), 256, 0, stream>>>(
                buf1, wt[l], bv[l], outf, outb, NN, 512, F);
        feat = buf0;
        F = 512;
    }
}

// Round 9
// 573.377 us; speedup vs baseline: 1.4043x; 1.4043x over previous
//
#include <hip/hip_runtime.h>

typedef unsigned short u16;
typedef unsigned int u32;

#define NN 8192
#define CAP 128

typedef __attribute__((ext_vector_type(8))) short short8;
typedef __attribute__((ext_vector_type(4))) float floatx4;

__device__ __forceinline__ u16 f2bf(float f) {
    union { float f; u32 i; } w;
    w.f = f;
    u32 i = w.i;
    u32 r = (i + 0x7FFFu + ((i >> 16) & 1u)) >> 16;
    return (u16)r;
}
__device__ __forceinline__ float lo_bf(u32 v) {
    union { u32 i; float f; } w;
    w.i = v << 16;
    return w.f;
}
__device__ __forceinline__ float hi_bf(u32 v) {
    union { u32 i; float f; } w;
    w.i = v & 0xFFFF0000u;
    return w.f;
}
__device__ __forceinline__ float softplusf(float x) {
    return fmaxf(x, 0.0f) + log1pf(expf(-fabsf(x)));
}

// ---------------- wave-per-row pass over f32 adjacency ----------------
// Symmetric matrix => deg_in == deg_out; one degree/norm array serves both.
__global__ __launch_bounds__(256) void build_graph(
    const float* __restrict__ adj, int* __restrict__ deg,
    float* __restrict__ snorm, u32* __restrict__ edges)
{
    const int wave = threadIdx.x >> 6, lane = threadIdx.x & 63;
    const int i = blockIdx.x * 4 + wave;
    __shared__ int cnt[4];
    if (threadIdx.x < 4) cnt[threadIdx.x] = 0;
    __syncthreads();
    const uint4* rowp = (const uint4*)(adj + (size_t)i * NN);
    u32* erow = edges + (size_t)i * CAP;
#pragma unroll 4
    for (int it = 0; it < 32; ++it) {            // 32 * 64 lanes * 4 f32 = 8192
        uint4 v = rowp[it * 64 + lane];
        int jb = (it * 64 + lane) * 4;
        u32 w[4] = { v.x, v.y, v.z, v.w };
#pragma unroll
        for (int e = 0; e < 4; ++e) {
            int j = jb + e;
            if ((i != j) && ((w[e] & 0x7FFFFFFFu) != 0)) {
                int slot = atomicAdd(&cnt[wave], 1);   // LDS atomic, wave-local
                if (slot < CAP) erow[slot] = (u32)j;
            }
        }
    }
    __syncthreads();
    if (lane == 0) {
        int c = cnt[wave];
        deg[i] = c;
        snorm[i] = rsqrtf((float)max(c, 1));
    }
}

// ---------------- concat [emb|pos] (f32), pre-scaled by snorm -> bf16 [8192x128] ----------------
__global__ void concat_feat(const float* __restrict__ emb, const float* __restrict__ pos,
                            const float* __restrict__ snorm, u16* __restrict__ out) {
    int idx = blockIdx.x * 256 + threadIdx.x;   // 8192*128 total
    int i = idx >> 7, f = idx & 127;
    float v = (f < 125) ? emb[i * 125 + f] : pos[i * 3 + (f - 125)];
    out[idx] = f2bf(v * snorm[i]);
}

// ---------------- all 4 weight transposes in one launch ----------------
__global__ void transpose_all(const float* __restrict__ W0, const float* __restrict__ W1,
                              const float* __restrict__ W2, const float* __restrict__ W3,
                              u16* __restrict__ T0, u16* __restrict__ T1,
                              u16* __restrict__ T2, u16* __restrict__ T3) {
    __shared__ float tile[32][33];
    const int z = blockIdx.z;
    const float* W = (z == 0) ? W0 : (z == 1) ? W1 : (z == 2) ? W2 : W3;
    u16* WT       = (z == 0) ? T0 : (z == 1) ? T1 : (z == 2) ? T2 : T3;
    const int K = (z == 0) ? 128 : 512;
    const int N = 512;
    int bx = blockIdx.x * 32;   // n
    int by = blockIdx.y * 32;   // k
    if (by >= K) return;
    int tx = threadIdx.x & 31, ty = threadIdx.x >> 5;  // 256 threads
#pragma unroll
    for (int yy = ty; yy < 32; yy += 8)
        tile[yy][tx] = W[(size_t)(by + yy) * N + bx + tx];
    __syncthreads();
#pragma unroll
    for (int yy = ty; yy < 32; yy += 8)
        WT[(size_t)(bx + yy) * K + by + tx] = f2bf(tile[tx][yy]);
}

// ---------------- SpMM: out[j,:] = snorm[j] * sum_{i in N(j)} featS[i,:] ----------------
// featS is PRE-SCALED by snorm[src]; inner loop = pure gather+accumulate.
__global__ __launch_bounds__(256) void spmm_kernel(
    const u32* __restrict__ edges, const int* __restrict__ deg,
    const float* __restrict__ snorm,
    const uint4* __restrict__ feat4, uint4* __restrict__ out4, int Fq /* = F/8 */)
{
    __shared__ int sh_i[4][CAP];
    const int wave = threadIdx.x >> 6, lane = threadIdx.x & 63;
    const int j = blockIdx.x * 4 + wave;
    const int cnt = min(deg[j], CAP);
    for (int c = lane; c < cnt; c += 64)
        sh_i[wave][c] = (int)edges[(size_t)j * CAP + c];
    __syncthreads();
    if (lane < Fq) {
        float a[8] = {};
#pragma unroll 4
        for (int c = 0; c < cnt; ++c) {
            uint4 v = feat4[(size_t)sh_i[wave][c] * Fq + lane];
            a[0] += lo_bf(v.x); a[1] += hi_bf(v.x);
            a[2] += lo_bf(v.y); a[3] += hi_bf(v.y);
            a[4] += lo_bf(v.z); a[5] += hi_bf(v.z);
            a[6] += lo_bf(v.w); a[7] += hi_bf(v.w);
        }
        float sj = snorm[j];
        uint4 o;
        o.x = (u32)f2bf(a[0] * sj) | ((u32)f2bf(a[1] * sj) << 16);
        o.y = (u32)f2bf(a[2] * sj) | ((u32)f2bf(a[3] * sj) << 16);
        o.z = (u32)f2bf(a[4] * sj) | ((u32)f2bf(a[5] * sj) << 16);
        o.w = (u32)f2bf(a[6] * sj) | ((u32)f2bf(a[7] * sj) << 16);
        out4[(size_t)j * Fq + lane] = o;
    }
}

// ---------------- GEMM: out = softplus(A[M,K] @ W + b) [* snorm[row] if inner layer] ----------------
// BM=64, BN=128, BK=32 (512 blocks = 2/CU); async global_load_lds width-16 staging.
__global__ __launch_bounds__(256, 2) void gemm_bias_softplus(
    const u16* __restrict__ A, const u16* __restrict__ BT,
    const float* __restrict__ bias, const float* __restrict__ snorm,
    float* __restrict__ outf, u16* __restrict__ outb,
    int M, int N, int K)
{
    __shared__ u16 lA[64 * 32];    // [m][k] 4KB
    __shared__ u16 lB[128 * 32];   // [n][k] 8KB
    const int tid = threadIdx.x;
    const int wave = tid >> 6;
    const int lane = tid & 63;
    const int q = lane >> 4;
    const int m16 = lane & 15;
    const int wm = (wave >> 1) * 32;
    const int wn = (wave & 1) * 64;
    const int bm = blockIdx.x, bn = blockIdx.y;

    const int srow = tid >> 2;            // 0..63
    const int scol = (tid & 3) * 8;       // element offset within 32-wide k-tile
    const u16* gA  = A  + (size_t)(bm * 64 + srow) * K + scol;
    const u16* gB0 = BT + (size_t)(bn * 128 + srow) * K + scol;
    const u16* gB1 = gB0 + (size_t)64 * K;
    u16* lAp  = lA + tid * 8;
    u16* lBp0 = lB + tid * 8;
    u16* lBp1 = lB + 2048 + tid * 8;

    floatx4 acc[2][4] = {};

    for (int k0 = 0; k0 < K; k0 += 32) {
        __builtin_amdgcn_global_load_lds(
            (const __attribute__((address_space(1))) u32*)(const void*)(gA + k0),
            (__attribute__((address_space(3))) u32*)(void*)lAp, 16, 0, 0);
        __builtin_amdgcn_global_load_lds(
            (const __attribute__((address_space(1))) u32*)(const void*)(gB0 + k0),
            (__attribute__((address_space(3))) u32*)(void*)lBp0, 16, 0, 0);
        __builtin_amdgcn_global_load_lds(
            (const __attribute__((address_space(1))) u32*)(const void*)(gB1 + k0),
            (__attribute__((address_space(3))) u32*)(void*)lBp1, 16, 0, 0);
        __syncthreads();   // barrier semantics drain vmcnt first

        short8 af[2], bfr[4];
#pragma unroll
        for (int im = 0; im < 2; ++im)
            af[im] = *(const short8*)&lA[(wm + im * 16 + m16) * 32 + q * 8];
#pragma unroll
        for (int in = 0; in < 4; ++in)
            bfr[in] = *(const short8*)&lB[(wn + in * 16 + m16) * 32 + q * 8];
#pragma unroll
        for (int im = 0; im < 2; ++im)
#pragma unroll
            for (int in = 0; in < 4; ++in)
                acc[im][in] = __builtin_amdgcn_mfma_f32_16x16x32_bf16(
                    af[im], bfr[in], acc[im][in], 0, 0, 0);
        __syncthreads();
    }

    // epilogue: C/D layout col = lane&15, row = q*4 + reg  [measured m89/m91]
#pragma unroll
    for (int im = 0; im < 2; ++im) {
#pragma unroll
        for (int in = 0; in < 4; ++in) {
            int col = bn * 128 + wn + in * 16 + m16;
            float bvf = bias[col];
#pragma unroll
            for (int r = 0; r < 4; ++r) {
                int row = bm * 64 + wm + im * 16 + q * 4 + r;
                float v = softplusf(acc[im][in][r] + bvf);
                if (outf) outf[(size_t)row * N + col] = v;
                else      outb[(size_t)row * N + col] = f2bf(v * snorm[row]);
            }
        }
    }
}

extern "C" void kernel_launch(void* const* d_in, const int* in_sizes, int n_in,
                              void* d_out, int out_size, void* d_ws, size_t ws_size,
                              hipStream_t stream)
{
    const float* atom_pos = (const float*)d_in[0];
    const float* dist_adj = (const float*)d_in[1];
    const float* atom_emb = (const float*)d_in[2];
    const float* Wm[4] = { (const float*)d_in[3], (const float*)d_in[5],
                           (const float*)d_in[7], (const float*)d_in[9] };
    const float* bv[4] = { (const float*)d_in[4], (const float*)d_in[6],
                           (const float*)d_in[8], (const float*)d_in[10] };

    char* p = (char*)d_ws;
    auto alloc = [&](size_t n) { char* r = p; p += (n + 255) & ~(size_t)255; return r; };
    int*   deg   = (int*)alloc(NN * 4);
    float* snorm = (float*)alloc(NN * 4);
    u32*   edges = (u32*)alloc((size_t)NN * CAP * 4);
    u16*   wt[4];
    wt[0] = (u16*)alloc(512 * 128 * 2);
    wt[1] = (u16*)alloc(512 * 512 * 2);
    wt[2] = (u16*)alloc(512 * 512 * 2);
    wt[3] = (u16*)alloc(512 * 512 * 2);
    u16* buf0 = (u16*)alloc((size_t)NN * 512 * 2);
    u16* buf1 = (u16*)alloc((size_t)NN * 512 * 2);

    build_graph<<<NN / 4, 256, 0, stream>>>(dist_adj, deg, snorm, edges);
    concat_feat<<<(NN * 128) / 256, 256, 0, stream>>>(atom_emb, atom_pos, snorm, buf0);
    transpose_all<<<dim3(16, 16, 4), 256, 0, stream>>>(
        Wm[0], Wm[1], Wm[2], Wm[3], wt[0], wt[1], wt[2], wt[3]);

    const u16* feat = buf0;
    int F = 128;
    for (int l = 0; l < 4; ++l) {
        spmm_kernel<<<NN / 4, 256, 0, stream>>>(edges, deg, snorm,
                                                (const uint4*)feat, (uint4*)buf1, F / 8);
        float* outf = (l == 3) ? (float*)d_out : nullptr;
        u16*   outb = (l == 3) ? nullptr : buf0;
        gemm_bias_softplus<<<dim3(NN / 64, 512 / 128), 256, 0, stream>>>(
            buf1, wt[l], bv[l], snorm, outf, outb, NN, 512, F);
        feat = buf0;
        F = 512;
    }
}